// Round 6
// baseline (440.577 us; speedup 1.0000x reference)
//
#include <hip/hip_runtime.h>
#include <hip/hip_bf16.h>

// Problem constants
#define BB 2
#define SS 2048
#define DD 1024
#define HH 16
#define HD 64
#define NREL 129
#define LOG2E 1.4426950408889634f
#define SCALEQ (LOG2E / 8.0f)   // folded into Q at projection time

typedef short s8v __attribute__((ext_vector_type(8)));
typedef float f4 __attribute__((ext_vector_type(4)));

#define MFMA_BF16 __builtin_amdgcn_mfma_f32_16x16x32_bf16

__device__ __forceinline__ float bf2f(unsigned short u) {
  union { unsigned int i; float f; } x; x.i = ((unsigned int)u) << 16; return x.f;
}
__device__ __forceinline__ unsigned short f2bf(float f) {
  union { float f; unsigned int i; } x; x.f = f;
  unsigned int r = x.i + 0x7fffu + ((x.i >> 16) & 1u);
  return (unsigned short)(r >> 16);
}
__device__ __forceinline__ unsigned int pk2bf(float a, float b) {
  union { __hip_bfloat162 h2; unsigned int u; } c;
  c.h2 = __float22bfloat162_rn(float2{a, b});
  return c.u;
}

// ---------------------------------------------------------------------------
// Weight transpose+convert: W fp32 [1024 k][1024 n] -> WT bf16 [1024 n][1024 k]
// grid (16, 16, 3), block 256
__global__ __launch_bounds__(256) void cvt_w(
    const float* __restrict__ Wq, const float* __restrict__ Wk,
    const float* __restrict__ Wv, unsigned short* __restrict__ WTbase) {
  __shared__ unsigned short tile[64][72];
  const int z = blockIdx.z;
  const float* in = (z == 0) ? Wq : (z == 1) ? Wk : Wv;
  unsigned short* out = WTbase + (long)z * DD * DD;
  const int c0 = blockIdx.x * 64, r0 = blockIdx.y * 64;
  const int t = threadIdx.x;
  const int r = t >> 2;
  #pragma unroll
  for (int j = 0; j < 4; ++j) {
    int cc = (t & 3) * 16 + j * 4;
    f4 v = *(const f4*)(in + (long)(r0 + r) * DD + c0 + cc);
    #pragma unroll
    for (int e = 0; e < 4; ++e) tile[r][cc + e] = f2bf(v[e]);
  }
  __syncthreads();
  const int c = t >> 2;
  #pragma unroll
  for (int h = 0; h < 2; ++h) {
    int r8 = (t & 3) + 4 * h;
    unsigned short vals[8];
    #pragma unroll
    for (int j = 0; j < 8; ++j) vals[j] = tile[r8 * 8 + j][c];
    *(s8v*)(out + (long)(c0 + c) * DD + r0 + r8 * 8) = *(s8v*)vals;
  }
}

// ---------------------------------------------------------------------------
// bf16 tile transpose (for V): out[b][c][r] = in[b][r][c]
__global__ __launch_bounds__(256) void transpose_bf16(
    const unsigned short* __restrict__ in, unsigned short* __restrict__ out,
    int R, int C, long inBatch, long outBatch) {
  __shared__ unsigned short tile[64][72];
  const int c0 = blockIdx.x * 64, r0 = blockIdx.y * 64;
  const unsigned short* ip = in + (long)blockIdx.z * inBatch;
  unsigned short* op = out + (long)blockIdx.z * outBatch;
  const int t = threadIdx.x;
  const int r = t >> 2;
  #pragma unroll
  for (int h = 0; h < 2; ++h) {
    int c8 = (t & 3) + 4 * h;
    *(s8v*)&tile[r][c8 * 8] = *(const s8v*)(ip + (long)(r0 + r) * C + c0 + c8 * 8);
  }
  __syncthreads();
  const int c = t >> 2;
  #pragma unroll
  for (int h = 0; h < 2; ++h) {
    int r8 = (t & 3) + 4 * h;
    unsigned short vals[8];
    #pragma unroll
    for (int j = 0; j < 8; ++j) vals[j] = tile[r8 * 8 + j][c];
    *(s8v*)(op + (long)(c0 + c) * R + r0 + r8 * 8) = *(s8v*)vals;
  }
}

// ---------------------------------------------------------------------------
// Fused QKV projection GEMM: C = X @ W + bias, head-split [bh][s][d] bf16.
// 128m x 128n tiles; wave owns 32m -> each LDS B-read feeds 2 MFMAs.
// Q output is pre-scaled by SCALEQ (folded softmax scale).
// grid (8, 32, 3), block 256.
__global__ __launch_bounds__(256, 3) void proj_gemm(
    const float* __restrict__ Xq, const float* __restrict__ Xk,
    const float* __restrict__ Xv, const unsigned short* __restrict__ WTbase,
    const float* __restrict__ bq, const float* __restrict__ bk,
    const float* __restrict__ bv,
    unsigned short* __restrict__ qbuf, unsigned short* __restrict__ kbuf,
    unsigned short* __restrict__ vbuf) {
  __shared__ unsigned short wt[128][72];
  const int z = blockIdx.z;
  const float* X = (z == 0) ? Xq : (z == 1) ? Xk : Xv;
  const unsigned short* WT = WTbase + (long)z * DD * DD;
  const float* bias = (z == 0) ? bq : (z == 1) ? bk : bv;
  unsigned short* out = (z == 0) ? qbuf : (z == 1) ? kbuf : vbuf;
  const float osc = (z == 0) ? SCALEQ : 1.0f;

  const int n0 = blockIdx.x * 128, m0 = blockIdx.y * 128;
  const int t = threadIdx.x, w = t >> 6, l = t & 63;
  const int lm = l & 15, qd = l >> 4;

  f4 acc[8][2];
  #pragma unroll
  for (int i = 0; i < 8; ++i) { acc[i][0] = (f4)0.0f; acc[i][1] = (f4)0.0f; }

  for (int k0 = 0; k0 < DD; k0 += 64) {
    __syncthreads();
    #pragma unroll
    for (int i = 0; i < 4; ++i) {
      int idx = t + i * 256;            // 0..1023
      int n = idx >> 3, kc = idx & 7;   // n 0..127
      *(s8v*)&wt[n][kc * 8] = *(const s8v*)(WT + (long)(n0 + n) * DD + k0 + kc * 8);
    }
    __syncthreads();
    s8v a[2][2];
    #pragma unroll
    for (int ms = 0; ms < 2; ++ms) {
      const float* xr = X + (long)(m0 + w * 32 + ms * 16 + lm) * DD + k0;
      f4 v0 = *(const f4*)(xr + qd * 8), v1 = *(const f4*)(xr + qd * 8 + 4);
      f4 v2 = *(const f4*)(xr + 32 + qd * 8), v3 = *(const f4*)(xr + 32 + qd * 8 + 4);
      unsigned int u[8];
      #pragma unroll
      for (int e = 0; e < 2; ++e) {
        u[e]     = pk2bf(v0[2 * e], v0[2 * e + 1]);
        u[2 + e] = pk2bf(v1[2 * e], v1[2 * e + 1]);
        u[4 + e] = pk2bf(v2[2 * e], v2[2 * e + 1]);
        u[6 + e] = pk2bf(v3[2 * e], v3[2 * e + 1]);
      }
      a[ms][0] = *(s8v*)u; a[ms][1] = *(s8v*)(u + 4);
    }
    #pragma unroll
    for (int cb = 0; cb < 8; ++cb) {
      s8v b0 = *(const s8v*)&wt[cb * 16 + lm][qd * 8];
      s8v b1 = *(const s8v*)&wt[cb * 16 + lm][32 + qd * 8];
      #pragma unroll
      for (int ms = 0; ms < 2; ++ms) {
        acc[cb][ms] = MFMA_BF16(a[ms][0], b0, acc[cb][ms], 0, 0, 0);
        acc[cb][ms] = MFMA_BF16(a[ms][1], b1, acc[cb][ms], 0, 0, 0);
      }
    }
  }
  #pragma unroll
  for (int cb = 0; cb < 8; ++cb) {
    int n = n0 + cb * 16 + lm;
    float bvv = bias[n];
    int h = n >> 6, d = n & 63;
    #pragma unroll
    for (int ms = 0; ms < 2; ++ms) {
      #pragma unroll
      for (int r = 0; r < 4; ++r) {
        int m = m0 + w * 32 + ms * 16 + qd * 4 + r;
        int b = m >> 11, s = m & (SS - 1);
        out[((long)(b * HH + h) * SS + s) * HD + d] = f2bf((acc[cb][ms][r] + bvv) * osc);
      }
    }
  }
}

// ---------------------------------------------------------------------------
// Flash attention, S-transposed (C col = q). Q pre-scaled; fast uniform-bias
// path off the diagonal band; K register double-buffer.
// grid (32 q-blocks, 32 bh), block 256 (4 waves x 16 q's each)
__global__ __launch_bounds__(256, 4) void attn(
    const unsigned short* __restrict__ qb, const unsigned short* __restrict__ kb,
    const unsigned short* __restrict__ vt, const float* __restrict__ tableF,
    const float* __restrict__ maskF, float* __restrict__ out) {
  __shared__ unsigned short pbuf[4][16][40]; // per-wave P (q-major rows)
  __shared__ float mk[SS];                   // mask row * LOG2E
  __shared__ unsigned short qr2[NREL][66];   // [dist][q_local] (pre-scaled)

  const int bh = blockIdx.y, b = bh >> 4, h = bh & 15;
  const int q0 = blockIdx.x * 64;
  const int t = threadIdx.x, w = t >> 6, l = t & 63;
  const int lm = l & 15, qd = l >> 4;

  // stage mask (pre-scaled by LOG2E)
  {
    const float* mrow = maskF + b * SS;
    f4 m0v = *(const f4*)(mrow + t * 8);
    f4 m1v = *(const f4*)(mrow + t * 8 + 4);
    #pragma unroll
    for (int e = 0; e < 4; ++e) {
      mk[t * 8 + e] = m0v[e] * LOG2E;
      mk[t * 8 + 4 + e] = m1v[e] * LOG2E;
    }
  }

  // Q fragments (q = q0 + w*16 + lm), already scaled by SCALEQ
  const unsigned short* qrow = qb + ((long)bh * SS + q0 + w * 16 + lm) * HD;
  const s8v qa0 = *(const s8v*)(qrow + qd * 8);
  const s8v qa1 = *(const s8v*)(qrow + 32 + qd * 8);

  // Fused qrel: qr2[dist][q_local] = q_scaled . table[dist]
  #pragma unroll
  for (int cb = 0; cb < 9; ++cb) {
    int dist = cb * 16 + lm;
    int dc = dist > NREL - 1 ? NREL - 1 : dist;
    const float* trow = tableF + dc * HD;
    f4 t0 = *(const f4*)(trow + qd * 8);
    f4 t1 = *(const f4*)(trow + qd * 8 + 4);
    f4 t2 = *(const f4*)(trow + 32 + qd * 8);
    f4 t3 = *(const f4*)(trow + 32 + qd * 8 + 4);
    unsigned int tb[8];
    tb[0] = pk2bf(t0[0], t0[1]); tb[1] = pk2bf(t0[2], t0[3]);
    tb[2] = pk2bf(t1[0], t1[1]); tb[3] = pk2bf(t1[2], t1[3]);
    tb[4] = pk2bf(t2[0], t2[1]); tb[5] = pk2bf(t2[2], t2[3]);
    tb[6] = pk2bf(t3[0], t3[1]); tb[7] = pk2bf(t3[2], t3[3]);
    s8v b0 = *(s8v*)tb, b1 = *(s8v*)(tb + 4);
    f4 c = MFMA_BF16(qa0, b0, (f4)0.0f, 0, 0, 0);
    c = MFMA_BF16(qa1, b1, c, 0, 0, 0);
    if (dist <= NREL - 1) {
      #pragma unroll
      for (int r = 0; r < 4; ++r)
        qr2[dist][w * 16 + qd * 4 + r] = f2bf(c[r]);
    }
  }
  __syncthreads();

  const int qcol = w * 16 + lm;                  // this lane's q (block-local)
  const float bLo = bf2f(qr2[0][qcol]);          // uniform bias, dist <= -64
  const float bHi = bf2f(qr2[128][qcol]);        // uniform bias, dist >= +64
  const int dqbase = 64 + qd * 4 - (q0 + qcol);

  float m_ = -1e30f, l_ = 0.0f;
  f4 c4[4];
  #pragma unroll
  for (int i = 0; i < 4; ++i) c4[i] = (f4)0.0f;

  const unsigned short* kbase = kb + ((long)bh * SS + lm) * HD;
  const unsigned short* vbase = vt + ((long)bh * HD + lm) * SS + qd * 8;

  s8v kA[4], kB[4];
  #define LOADK(k0, ka)                                                \
    {                                                                  \
      const unsigned short* kr = kbase + (long)(k0) * HD;              \
      ka[0] = *(const s8v*)(kr + qd * 8);                              \
      ka[1] = *(const s8v*)(kr + 32 + qd * 8);                         \
      ka[2] = *(const s8v*)(kr + 16 * HD + qd * 8);                    \
      ka[3] = *(const s8v*)(kr + 16 * HD + 32 + qd * 8);               \
    }

  LOADK(0, kA);

  #define BODY(ka, k0)                                                           \
    {                                                                            \
      /* V^T fragments issued first; softmax hides their latency */              \
      s8v va0 = *(const s8v*)(vbase + (k0));                                     \
      s8v va1 = *(const s8v*)(vbase + 16 * SS + (k0));                           \
      s8v va2 = *(const s8v*)(vbase + 32 * SS + (k0));                           \
      s8v va3 = *(const s8v*)(vbase + 48 * SS + (k0));                           \
      f4 st0 = MFMA_BF16(ka[0], qa0, (f4)0.0f, 0, 0, 0);                         \
      st0 = MFMA_BF16(ka[1], qa1, st0, 0, 0, 0);                                 \
      f4 st1 = MFMA_BF16(ka[2], qa0, (f4)0.0f, 0, 0, 0);                         \
      st1 = MFMA_BF16(ka[3], qa1, st1, 0, 0, 0);                                 \
      f4 mk0v = *(const f4*)&mk[(k0) + qd * 4];                                  \
      f4 mk1v = *(const f4*)&mk[(k0) + 16 + qd * 4];                             \
      float z[8];                                                                \
      const int diff = (k0) - q0;                                                \
      if (diff >= 128) {                                                         \
        _Pragma("unroll") for (int r = 0; r < 4; ++r) {                          \
          z[r] = st0[r] + bHi + mk0v[r];                                         \
          z[4 + r] = st1[r] + bHi + mk1v[r];                                     \
        }                                                                        \
      } else if (diff <= -96) {                                                  \
        _Pragma("unroll") for (int r = 0; r < 4; ++r) {                          \
          z[r] = st0[r] + bLo + mk0v[r];                                         \
          z[4 + r] = st1[r] + bLo + mk1v[r];                                     \
        }                                                                        \
      } else {                                                                   \
        const int db0 = dqbase + (k0);                                           \
        _Pragma("unroll") for (int r = 0; r < 4; ++r) {                          \
          int d0 = db0 + r;      d0 = d0 < 0 ? 0 : (d0 > 128 ? 128 : d0);        \
          int d1 = db0 + 16 + r; d1 = d1 < 0 ? 0 : (d1 > 128 ? 128 : d1);        \
          z[r] = st0[r] + bf2f(qr2[d0][qcol]) + mk0v[r];                         \
          z[4 + r] = st1[r] + bf2f(qr2[d1][qcol]) + mk1v[r];                     \
        }                                                                        \
      }                                                                          \
      float tm = fmaxf(fmaxf(fmaxf(z[0], z[1]), fmaxf(z[2], z[3])),              \
                       fmaxf(fmaxf(z[4], z[5]), fmaxf(z[6], z[7])));             \
      tm = fmaxf(tm, __shfl_xor(tm, 16));                                        \
      tm = fmaxf(tm, __shfl_xor(tm, 32));                                        \
      float mn = fmaxf(m_, tm);                                                  \
      float alpha = __builtin_amdgcn_exp2f(m_ - mn);                             \
      m_ = mn;                                                                   \
      float p[8];                                                                \
      _Pragma("unroll") for (int i = 0; i < 8; ++i)                              \
          p[i] = __builtin_amdgcn_exp2f(z[i] - mn);                              \
      float ts = ((p[0] + p[1]) + (p[2] + p[3])) + ((p[4] + p[5]) + (p[6] + p[7])); \
      ts += __shfl_xor(ts, 16);                                                  \
      ts += __shfl_xor(ts, 32);                                                  \
      l_ = l_ * alpha + ts;                                                      \
      _Pragma("unroll") for (int db = 0; db < 4; ++db)                           \
          _Pragma("unroll") for (int r = 0; r < 4; ++r) c4[db][r] *= alpha;      \
      *(unsigned int*)&pbuf[w][lm][qd * 4] = pk2bf(p[0], p[1]);                  \
      *(unsigned int*)&pbuf[w][lm][qd * 4 + 2] = pk2bf(p[2], p[3]);              \
      *(unsigned int*)&pbuf[w][lm][16 + qd * 4] = pk2bf(p[4], p[5]);             \
      *(unsigned int*)&pbuf[w][lm][16 + qd * 4 + 2] = pk2bf(p[6], p[7]);         \
      asm volatile("s_waitcnt lgkmcnt(0)" ::: "memory");                         \
      s8v pa = *(const s8v*)&pbuf[w][lm][qd * 8];                                \
      c4[0] = MFMA_BF16(va0, pa, c4[0], 0, 0, 0);                                \
      c4[1] = MFMA_BF16(va1, pa, c4[1], 0, 0, 0);                                \
      c4[2] = MFMA_BF16(va2, pa, c4[2], 0, 0, 0);                                \
      c4[3] = MFMA_BF16(va3, pa, c4[3], 0, 0, 0);                                \
    }

  for (int k0 = 0; k0 < SS; k0 += 64) {
    LOADK(k0 + 32, kB);
    BODY(kA, k0);
    if (k0 + 64 < SS) LOADK(k0 + 64, kA);
    BODY(kB, k0 + 32);
  }

  // epilogue: O^T[d][q] -> out[b][s][d], f4 stores
  const float inv = 1.0f / l_;
  float* obase = out + ((long)b * SS + q0 + qcol) * DD + h * HD;
  #pragma unroll
  for (int db = 0; db < 4; ++db) {
    f4 o;
    #pragma unroll
    for (int r = 0; r < 4; ++r) o[r] = c4[db][r] * inv;
    *(f4*)(obase + db * 16 + qd * 4) = o;
  }
}

// ---------------------------------------------------------------------------
extern "C" void kernel_launch(void* const* d_in, const int* in_sizes, int n_in,
                              void* d_out, int out_size, void* d_ws, size_t ws_size,
                              hipStream_t stream) {
  const float* query = (const float*)d_in[0];
  const float* key   = (const float*)d_in[1];
  const float* value = (const float*)d_in[2];
  const float* mask  = (const float*)d_in[3];
  const float* Wq    = (const float*)d_in[4];
  const float* bq    = (const float*)d_in[5];
  const float* Wk    = (const float*)d_in[6];
  const float* bk    = (const float*)d_in[7];
  const float* Wv    = (const float*)d_in[8];
  const float* bv    = (const float*)d_in[9];
  const float* table = (const float*)d_in[10];

  char* ws = (char*)d_ws;
  // workspace layout (bytes), span 40 MB
  unsigned short* WT   = (unsigned short*)(ws);               // 6,291,456
  unsigned short* qbuf = (unsigned short*)(ws + (8l << 20));
  unsigned short* kbuf = (unsigned short*)(ws + (16l << 20));
  unsigned short* vbuf = (unsigned short*)(ws + (24l << 20));
  unsigned short* vT   = (unsigned short*)(ws + (32l << 20));

  // 1) transpose+convert weights: WT[z][n][k] = W[z][k][n]
  cvt_w<<<dim3(16, 16, 3), 256, 0, stream>>>(Wq, Wk, Wv, WT);

  // 2) fused QKV projections -> head-split bf16 [bh][s][d] (Q pre-scaled)
  proj_gemm<<<dim3(8, 32, 3), 256, 0, stream>>>(query, key, value, WT,
                                                bq, bk, bv, qbuf, kbuf, vbuf);

  // 3) transpose V per (b,h): vT[bh][d][s]
  transpose_bf16<<<dim3(1, 32, 32), 256, 0, stream>>>(vbuf, vT, 2048, 64,
                                                      (long)2048 * 64, (long)2048 * 64);

  // 4) flash attention (S-transposed), fp32 output
  attn<<<dim3(32, 32, 1), 256, 0, stream>>>(qbuf, kbuf, vT, table, mask,
                                            (float*)d_out);
}

// Round 7
// 311.366 us; speedup vs baseline: 1.4150x; 1.4150x over previous
//
#include <hip/hip_runtime.h>
#include <hip/hip_bf16.h>

// Problem constants
#define BB 2
#define SS 2048
#define DD 1024
#define HH 16
#define HD 64
#define NREL 129
#define LOG2E 1.4426950408889634f
#define SCALEQ (LOG2E / 8.0f)   // folded into Q at projection time

typedef short s8v __attribute__((ext_vector_type(8)));
typedef short s4v __attribute__((ext_vector_type(4)));
typedef float f4 __attribute__((ext_vector_type(4)));

#define MFMA_BF16 __builtin_amdgcn_mfma_f32_16x16x32_bf16

__device__ __forceinline__ float bf2f(unsigned short u) {
  union { unsigned int i; float f; } x; x.i = ((unsigned int)u) << 16; return x.f;
}
__device__ __forceinline__ unsigned short f2bf(float f) {
  union { float f; unsigned int i; } x; x.f = f;
  unsigned int r = x.i + 0x7fffu + ((x.i >> 16) & 1u);
  return (unsigned short)(r >> 16);
}
__device__ __forceinline__ unsigned int pk2bf(float a, float b) {
  union { __hip_bfloat162 h2; unsigned int u; } c;
  c.h2 = __float22bfloat162_rn(float2{a, b});
  return c.u;
}
// async global->LDS DMA, 16B/lane; LDS dest = uniform base + lane*16
__device__ __forceinline__ void gl_lds16(const void* g, void* l) {
  __builtin_amdgcn_global_load_lds(
      (const __attribute__((address_space(1))) unsigned int*)g,
      (__attribute__((address_space(3))) unsigned int*)l, 16, 0, 0);
}

// ---------------------------------------------------------------------------
// Weight transpose+convert: W fp32 [1024 k][1024 n] -> WT bf16 [1024 n][1024 k]
// grid (16, 16, 3), block 256
__global__ __launch_bounds__(256) void cvt_w(
    const float* __restrict__ Wq, const float* __restrict__ Wk,
    const float* __restrict__ Wv, unsigned short* __restrict__ WTbase) {
  __shared__ unsigned short tile[64][72];
  const int z = blockIdx.z;
  const float* in = (z == 0) ? Wq : (z == 1) ? Wk : Wv;
  unsigned short* out = WTbase + (long)z * DD * DD;
  const int c0 = blockIdx.x * 64, r0 = blockIdx.y * 64;
  const int t = threadIdx.x;
  const int r = t >> 2;
  #pragma unroll
  for (int j = 0; j < 4; ++j) {
    int cc = (t & 3) * 16 + j * 4;
    f4 v = *(const f4*)(in + (long)(r0 + r) * DD + c0 + cc);
    #pragma unroll
    for (int e = 0; e < 4; ++e) tile[r][cc + e] = f2bf(v[e]);
  }
  __syncthreads();
  const int c = t >> 2;
  #pragma unroll
  for (int h = 0; h < 2; ++h) {
    int r8 = (t & 3) + 4 * h;
    unsigned short vals[8];
    #pragma unroll
    for (int j = 0; j < 8; ++j) vals[j] = tile[r8 * 8 + j][c];
    *(s8v*)(out + (long)(c0 + c) * DD + r0 + r8 * 8) = *(s8v*)vals;
  }
}

// ---------------------------------------------------------------------------
// Fused QKV projection GEMM: C = X @ W + bias.
// Q,K written head-split [bh][s][d]; V written TRANSPOSED [bh][d][s] directly.
// Q pre-scaled by SCALEQ. grid (8, 32, 3), block 256.
__global__ __launch_bounds__(256, 3) void proj_gemm(
    const float* __restrict__ Xq, const float* __restrict__ Xk,
    const float* __restrict__ Xv, const unsigned short* __restrict__ WTbase,
    const float* __restrict__ bq, const float* __restrict__ bk,
    const float* __restrict__ bv,
    unsigned short* __restrict__ qbuf, unsigned short* __restrict__ kbuf,
    unsigned short* __restrict__ vTbuf) {
  __shared__ unsigned short wt[128][72];
  const int z = blockIdx.z;
  const float* X = (z == 0) ? Xq : (z == 1) ? Xk : Xv;
  const unsigned short* WT = WTbase + (long)z * DD * DD;
  const float* bias = (z == 0) ? bq : (z == 1) ? bk : bv;
  const float osc = (z == 0) ? SCALEQ : 1.0f;

  const int n0 = blockIdx.x * 128, m0 = blockIdx.y * 128;
  const int t = threadIdx.x, w = t >> 6, l = t & 63;
  const int lm = l & 15, qd = l >> 4;

  f4 acc[8][2];
  #pragma unroll
  for (int i = 0; i < 8; ++i) { acc[i][0] = (f4)0.0f; acc[i][1] = (f4)0.0f; }

  for (int k0 = 0; k0 < DD; k0 += 64) {
    __syncthreads();
    #pragma unroll
    for (int i = 0; i < 4; ++i) {
      int idx = t + i * 256;
      int n = idx >> 3, kc = idx & 7;
      *(s8v*)&wt[n][kc * 8] = *(const s8v*)(WT + (long)(n0 + n) * DD + k0 + kc * 8);
    }
    __syncthreads();
    s8v a[2][2];
    #pragma unroll
    for (int ms = 0; ms < 2; ++ms) {
      const float* xr = X + (long)(m0 + w * 32 + ms * 16 + lm) * DD + k0;
      f4 v0 = *(const f4*)(xr + qd * 8), v1 = *(const f4*)(xr + qd * 8 + 4);
      f4 v2 = *(const f4*)(xr + 32 + qd * 8), v3 = *(const f4*)(xr + 32 + qd * 8 + 4);
      unsigned int u[8];
      u[0] = pk2bf(v0[0], v0[1]); u[1] = pk2bf(v0[2], v0[3]);
      u[2] = pk2bf(v1[0], v1[1]); u[3] = pk2bf(v1[2], v1[3]);
      u[4] = pk2bf(v2[0], v2[1]); u[5] = pk2bf(v2[2], v2[3]);
      u[6] = pk2bf(v3[0], v3[1]); u[7] = pk2bf(v3[2], v3[3]);
      a[ms][0] = *(s8v*)u; a[ms][1] = *(s8v*)(u + 4);
    }
    #pragma unroll
    for (int cb = 0; cb < 8; ++cb) {
      s8v b0 = *(const s8v*)&wt[cb * 16 + lm][qd * 8];
      s8v b1 = *(const s8v*)&wt[cb * 16 + lm][32 + qd * 8];
      #pragma unroll
      for (int ms = 0; ms < 2; ++ms) {
        acc[cb][ms] = MFMA_BF16(a[ms][0], b0, acc[cb][ms], 0, 0, 0);
        acc[cb][ms] = MFMA_BF16(a[ms][1], b1, acc[cb][ms], 0, 0, 0);
      }
    }
  }
  if (z == 2) {
    // V: write transposed [bh][d][s], 8B vector stores (r -> s contiguous)
    #pragma unroll
    for (int cb = 0; cb < 8; ++cb) {
      int n = n0 + cb * 16 + lm;
      float bvv = bias[n];
      int hh = n >> 6, d = n & 63;
      #pragma unroll
      for (int ms = 0; ms < 2; ++ms) {
        int m = m0 + w * 32 + ms * 16 + qd * 4;
        int bidx = m >> 11, s = m & (SS - 1);
        unsigned short o4[4];
        #pragma unroll
        for (int r = 0; r < 4; ++r) o4[r] = f2bf(acc[cb][ms][r] + bvv);
        *(s4v*)&vTbuf[((long)(bidx * HH + hh) * HD + d) * SS + s] = *(s4v*)o4;
      }
    }
  } else {
    unsigned short* out = (z == 0) ? qbuf : kbuf;
    #pragma unroll
    for (int cb = 0; cb < 8; ++cb) {
      int n = n0 + cb * 16 + lm;
      float bvv = bias[n];
      int hh = n >> 6, d = n & 63;
      #pragma unroll
      for (int ms = 0; ms < 2; ++ms) {
        #pragma unroll
        for (int r = 0; r < 4; ++r) {
          int m = m0 + w * 32 + ms * 16 + qd * 4 + r;
          int bidx = m >> 11, s = m & (SS - 1);
          out[((long)(bidx * HH + hh) * SS + s) * HD + d] = f2bf((acc[cb][ms][r] + bvv) * osc);
        }
      }
    }
  }
}

// ---------------------------------------------------------------------------
// Flash attention, S-transposed, with double-buffered global_load_lds K/V
// staging shared by all 4 waves. 64 keys per round, 32 rounds.
// grid (32 q-blocks, 32 bh), block 256.
__global__ __launch_bounds__(256, 2) void attn(
    const unsigned short* __restrict__ qb, const unsigned short* __restrict__ kb,
    const unsigned short* __restrict__ vt, const float* __restrict__ tableF,
    const float* __restrict__ maskF, float* __restrict__ out) {
  __shared__ __align__(16) unsigned short ks[2][8][64][8];  // [buf][d-chunk][key][8d] 16KB
  __shared__ __align__(16) unsigned short vs[2][8][64][8];  // [buf][k-chunk][d][8k]  16KB
  __shared__ __align__(16) unsigned short qr2[NREL][66];    // [dist][q_local] 17KB
  __shared__ __align__(16) unsigned short pbuf[4][16][40];  // per-wave P, 2-phase 5KB
  __shared__ float mk[SS];                                  // mask*LOG2E 8KB

  const int bh = blockIdx.y, b = bh >> 4, h = bh & 15;
  const int q0 = blockIdx.x * 64;
  const int t = threadIdx.x, w = t >> 6, l = t & 63;
  const int lm = l & 15, qd = l >> 4;

  const unsigned short* kkb = kb + (long)bh * SS * HD;
  const unsigned short* vvb = vt + (long)bh * HD * SS;
  const int c0s = 2 * w, c1s = c0s + 1;

  // stage round 0 (keys 0..63) into buf 0 (async; overlaps prologue below)
  gl_lds16(kkb + (long)l * HD + c0s * 8, &ks[0][c0s][0][0]);
  gl_lds16(kkb + (long)l * HD + c1s * 8, &ks[0][c1s][0][0]);
  gl_lds16(vvb + (long)l * SS + c0s * 8, &vs[0][c0s][0][0]);
  gl_lds16(vvb + (long)l * SS + c1s * 8, &vs[0][c1s][0][0]);

  // stage mask (pre-scaled by LOG2E)
  {
    const float* mrow = maskF + b * SS;
    f4 m0v = *(const f4*)(mrow + t * 8);
    f4 m1v = *(const f4*)(mrow + t * 8 + 4);
    #pragma unroll
    for (int e = 0; e < 4; ++e) {
      mk[t * 8 + e] = m0v[e] * LOG2E;
      mk[t * 8 + 4 + e] = m1v[e] * LOG2E;
    }
  }

  // Q fragments (q = q0 + w*16 + lm), pre-scaled by SCALEQ
  const unsigned short* qrow = qb + ((long)bh * SS + q0 + w * 16 + lm) * HD;
  const s8v qa0 = *(const s8v*)(qrow + qd * 8);
  const s8v qa1 = *(const s8v*)(qrow + 32 + qd * 8);

  // Fused qrel: qr2[dist][q_local] = q_scaled . table[dist]
  #pragma unroll
  for (int cb = 0; cb < 9; ++cb) {
    int dist = cb * 16 + lm;
    int dc = dist > NREL - 1 ? NREL - 1 : dist;
    const float* trow = tableF + dc * HD;
    f4 t0 = *(const f4*)(trow + qd * 8);
    f4 t1 = *(const f4*)(trow + qd * 8 + 4);
    f4 t2 = *(const f4*)(trow + 32 + qd * 8);
    f4 t3 = *(const f4*)(trow + 32 + qd * 8 + 4);
    unsigned int tb[8];
    tb[0] = pk2bf(t0[0], t0[1]); tb[1] = pk2bf(t0[2], t0[3]);
    tb[2] = pk2bf(t1[0], t1[1]); tb[3] = pk2bf(t1[2], t1[3]);
    tb[4] = pk2bf(t2[0], t2[1]); tb[5] = pk2bf(t2[2], t2[3]);
    tb[6] = pk2bf(t3[0], t3[1]); tb[7] = pk2bf(t3[2], t3[3]);
    s8v b0 = *(s8v*)tb, b1 = *(s8v*)(tb + 4);
    f4 c = MFMA_BF16(qa0, b0, (f4)0.0f, 0, 0, 0);
    c = MFMA_BF16(qa1, b1, c, 0, 0, 0);
    if (dist <= NREL - 1) {
      #pragma unroll
      for (int r = 0; r < 4; ++r)
        qr2[dist][w * 16 + qd * 4 + r] = f2bf(c[r]);
    }
  }
  asm volatile("s_waitcnt vmcnt(0)" ::: "memory");
  __syncthreads();

  const int qcol = w * 16 + lm;
  const float bLo = bf2f(qr2[0][qcol]);     // uniform bias, dist <= -64
  const float bHi = bf2f(qr2[128][qcol]);   // uniform bias, dist >= +64

  float m_ = -1e30f, l_ = 0.0f;
  f4 c4[4];
  #pragma unroll
  for (int i = 0; i < 4; ++i) c4[i] = (f4)0.0f;

  for (int rr = 0; rr < 32; ++rr) {
    const int kk = rr << 6;
    const int buf = rr & 1;
    // async prefetch next round into other buffer
    if (rr < 31) {
      const int nb = buf ^ 1;
      const long kof = kk + 64;
      gl_lds16(kkb + (kof + l) * HD + c0s * 8, &ks[nb][c0s][0][0]);
      gl_lds16(kkb + (kof + l) * HD + c1s * 8, &ks[nb][c1s][0][0]);
      gl_lds16(vvb + (long)l * SS + kof + c0s * 8, &vs[nb][c0s][0][0]);
      gl_lds16(vvb + (long)l * SS + kof + c1s * 8, &vs[nb][c1s][0][0]);
    }
    // QK^T: 4 key-tiles of 16
    f4 st[4];
    #pragma unroll
    for (int tt = 0; tt < 4; ++tt) {
      s8v k0v = *(const s8v*)&ks[buf][qd][tt * 16 + lm][0];
      s8v k1v = *(const s8v*)&ks[buf][4 + qd][tt * 16 + lm][0];
      st[tt] = MFMA_BF16(k0v, qa0, (f4)0.0f, 0, 0, 0);
      st[tt] = MFMA_BF16(k1v, qa1, st[tt], 0, 0, 0);
    }
    // bias + mask -> z[16]
    float z[16];
    const int kband = kk - q0;
    if (kband >= 128) {
      #pragma unroll
      for (int tt = 0; tt < 4; ++tt) {
        f4 mv = *(const f4*)&mk[kk + tt * 16 + qd * 4];
        #pragma unroll
        for (int r = 0; r < 4; ++r) z[tt * 4 + r] = st[tt][r] + bHi + mv[r];
      }
    } else if (kband <= -128) {
      #pragma unroll
      for (int tt = 0; tt < 4; ++tt) {
        f4 mv = *(const f4*)&mk[kk + tt * 16 + qd * 4];
        #pragma unroll
        for (int r = 0; r < 4; ++r) z[tt * 4 + r] = st[tt][r] + bLo + mv[r];
      }
    } else {
      const int dbb = kband - qcol + 64 + qd * 4;
      #pragma unroll
      for (int tt = 0; tt < 4; ++tt) {
        f4 mv = *(const f4*)&mk[kk + tt * 16 + qd * 4];
        #pragma unroll
        for (int r = 0; r < 4; ++r) {
          int d = dbb + tt * 16 + r;
          d = d < 0 ? 0 : (d > 128 ? 128 : d);
          z[tt * 4 + r] = st[tt][r] + bf2f(qr2[d][qcol]) + mv[r];
        }
      }
    }
    // online softmax over 16 in-lane + 2 cross-quad shuffles
    float tm = z[0];
    #pragma unroll
    for (int i = 1; i < 16; ++i) tm = fmaxf(tm, z[i]);
    tm = fmaxf(tm, __shfl_xor(tm, 16));
    tm = fmaxf(tm, __shfl_xor(tm, 32));
    float mn = fmaxf(m_, tm);
    float alpha = __builtin_amdgcn_exp2f(m_ - mn);
    m_ = mn;
    float p[16];
    #pragma unroll
    for (int i = 0; i < 16; ++i) p[i] = __builtin_amdgcn_exp2f(z[i] - mn);
    float ts = 0.0f;
    #pragma unroll
    for (int i = 0; i < 16; ++i) ts += p[i];
    ts += __shfl_xor(ts, 16);
    ts += __shfl_xor(ts, 32);
    l_ = l_ * alpha + ts;
    #pragma unroll
    for (int db = 0; db < 4; ++db)
      #pragma unroll
      for (int r = 0; r < 4; ++r) c4[db][r] *= alpha;

    // PV phase A (keys 0..31)
    *(unsigned int*)&pbuf[w][lm][qd * 4] = pk2bf(p[0], p[1]);
    *(unsigned int*)&pbuf[w][lm][qd * 4 + 2] = pk2bf(p[2], p[3]);
    *(unsigned int*)&pbuf[w][lm][16 + qd * 4] = pk2bf(p[4], p[5]);
    *(unsigned int*)&pbuf[w][lm][16 + qd * 4 + 2] = pk2bf(p[6], p[7]);
    asm volatile("s_waitcnt lgkmcnt(0)" ::: "memory");
    {
      s8v pa = *(const s8v*)&pbuf[w][lm][qd * 8];
      #pragma unroll
      for (int db = 0; db < 4; ++db) {
        s8v va = *(const s8v*)&vs[buf][qd][db * 16 + lm][0];
        c4[db] = MFMA_BF16(va, pa, c4[db], 0, 0, 0);
      }
    }
    // PV phase B (keys 32..63)
    *(unsigned int*)&pbuf[w][lm][qd * 4] = pk2bf(p[8], p[9]);
    *(unsigned int*)&pbuf[w][lm][qd * 4 + 2] = pk2bf(p[10], p[11]);
    *(unsigned int*)&pbuf[w][lm][16 + qd * 4] = pk2bf(p[12], p[13]);
    *(unsigned int*)&pbuf[w][lm][16 + qd * 4 + 2] = pk2bf(p[14], p[15]);
    asm volatile("s_waitcnt lgkmcnt(0)" ::: "memory");
    {
      s8v pb = *(const s8v*)&pbuf[w][lm][qd * 8];
      #pragma unroll
      for (int db = 0; db < 4; ++db) {
        s8v vb = *(const s8v*)&vs[buf][4 + qd][db * 16 + lm][0];
        c4[db] = MFMA_BF16(vb, pb, c4[db], 0, 0, 0);
      }
    }
    // drain this round's DMA, then block-wide sync before buffer swap
    asm volatile("s_waitcnt vmcnt(0)" ::: "memory");
    __syncthreads();
  }

  // epilogue: O^T[d][q] -> out[b][s][d], f4 stores
  const float inv = 1.0f / l_;
  float* obase = out + ((long)b * SS + q0 + qcol) * DD + h * HD;
  #pragma unroll
  for (int db = 0; db < 4; ++db) {
    f4 o;
    #pragma unroll
    for (int r = 0; r < 4; ++r) o[r] = c4[db][r] * inv;
    *(f4*)(obase + db * 16 + qd * 4) = o;
  }
}

// ---------------------------------------------------------------------------
extern "C" void kernel_launch(void* const* d_in, const int* in_sizes, int n_in,
                              void* d_out, int out_size, void* d_ws, size_t ws_size,
                              hipStream_t stream) {
  const float* query = (const float*)d_in[0];
  const float* key   = (const float*)d_in[1];
  const float* value = (const float*)d_in[2];
  const float* mask  = (const float*)d_in[3];
  const float* Wq    = (const float*)d_in[4];
  const float* bq    = (const float*)d_in[5];
  const float* Wk    = (const float*)d_in[6];
  const float* bk    = (const float*)d_in[7];
  const float* Wv    = (const float*)d_in[8];
  const float* bv    = (const float*)d_in[9];
  const float* table = (const float*)d_in[10];

  char* ws = (char*)d_ws;
  // workspace layout (bytes), span 32 MB
  unsigned short* WT   = (unsigned short*)(ws);               // 6,291,456
  unsigned short* qbuf = (unsigned short*)(ws + (8l << 20));
  unsigned short* kbuf = (unsigned short*)(ws + (16l << 20));
  unsigned short* vT   = (unsigned short*)(ws + (24l << 20));

  // 1) transpose+convert weights: WT[z][n][k] = W[z][k][n]
  cvt_w<<<dim3(16, 16, 3), 256, 0, stream>>>(Wq, Wk, Wv, WT);

  // 2) fused QKV projections; V written pre-transposed [bh][d][s]
  proj_gemm<<<dim3(8, 32, 3), 256, 0, stream>>>(query, key, value, WT,
                                                bq, bk, bv, qbuf, kbuf, vT);

  // 3) flash attention (S-transposed, LDS-staged K/V), fp32 output
  attn<<<dim3(32, 32, 1), 256, 0, stream>>>(qbuf, kbuf, vT, table, mask,
                                            (float*)d_out);
}

// Round 8
// 285.330 us; speedup vs baseline: 1.5441x; 1.0912x over previous
//
#include <hip/hip_runtime.h>
#include <hip/hip_bf16.h>

// Problem constants
#define BB 2
#define SS 2048
#define DD 1024
#define HH 16
#define HD 64
#define NREL 129
#define LOG2E 1.4426950408889634f
#define SCALEQ (LOG2E / 8.0f)   // folded into Q at projection time

typedef short s8v __attribute__((ext_vector_type(8)));
typedef short s4v __attribute__((ext_vector_type(4)));
typedef float f4 __attribute__((ext_vector_type(4)));

#define MFMA_BF16 __builtin_amdgcn_mfma_f32_16x16x32_bf16

__device__ __forceinline__ float bf2f(unsigned short u) {
  union { unsigned int i; float f; } x; x.i = ((unsigned int)u) << 16; return x.f;
}
__device__ __forceinline__ unsigned short f2bf(float f) {
  union { float f; unsigned int i; } x; x.f = f;
  unsigned int r = x.i + 0x7fffu + ((x.i >> 16) & 1u);
  return (unsigned short)(r >> 16);
}
__device__ __forceinline__ unsigned int pk2bf(float a, float b) {
  union { __hip_bfloat162 h2; unsigned int u; } c;
  c.h2 = __float22bfloat162_rn(float2{a, b});
  return c.u;
}
// async global->LDS DMA, 16B/lane; LDS dest = uniform base + lane*16
__device__ __forceinline__ void gl_lds16(const void* g, void* l) {
  __builtin_amdgcn_global_load_lds(
      (const __attribute__((address_space(1))) unsigned int*)g,
      (__attribute__((address_space(3))) unsigned int*)l, 16, 0, 0);
}

// ---------------------------------------------------------------------------
// fp32 -> bf16 convert of the 3 input tensors [4096][1024] -> xb [3][4096*1024]
// grid (2048, 3), block 256, 8 elems/thread
__global__ __launch_bounds__(256) void cvt_x(
    const float* __restrict__ xq, const float* __restrict__ xk,
    const float* __restrict__ xv, unsigned short* __restrict__ xb) {
  const int z = blockIdx.y;
  const float* in = (z == 0) ? xq : (z == 1) ? xk : xv;
  unsigned short* out = xb + (long)z * 4096 * DD;
  const long i = ((long)blockIdx.x * 256 + threadIdx.x) * 8;
  f4 a = *(const f4*)(in + i);
  f4 b = *(const f4*)(in + i + 4);
  unsigned int u[4];
  u[0] = pk2bf(a[0], a[1]); u[1] = pk2bf(a[2], a[3]);
  u[2] = pk2bf(b[0], b[1]); u[3] = pk2bf(b[2], b[3]);
  *(s8v*)(out + i) = *(s8v*)u;
}

// ---------------------------------------------------------------------------
// Weight transpose+convert: W fp32 [1024 k][1024 n] -> WT bf16 [1024 n][1024 k]
// grid (16, 16, 3), block 256
__global__ __launch_bounds__(256) void cvt_w(
    const float* __restrict__ Wq, const float* __restrict__ Wk,
    const float* __restrict__ Wv, unsigned short* __restrict__ WTbase) {
  __shared__ unsigned short tile[64][72];
  const int z = blockIdx.z;
  const float* in = (z == 0) ? Wq : (z == 1) ? Wk : Wv;
  unsigned short* out = WTbase + (long)z * DD * DD;
  const int c0 = blockIdx.x * 64, r0 = blockIdx.y * 64;
  const int t = threadIdx.x;
  const int r = t >> 2;
  #pragma unroll
  for (int j = 0; j < 4; ++j) {
    int cc = (t & 3) * 16 + j * 4;
    f4 v = *(const f4*)(in + (long)(r0 + r) * DD + c0 + cc);
    #pragma unroll
    for (int e = 0; e < 4; ++e) tile[r][cc + e] = f2bf(v[e]);
  }
  __syncthreads();
  const int c = t >> 2;
  #pragma unroll
  for (int h = 0; h < 2; ++h) {
    int r8 = (t & 3) + 4 * h;
    unsigned short vals[8];
    #pragma unroll
    for (int j = 0; j < 8; ++j) vals[j] = tile[r8 * 8 + j][c];
    *(s8v*)(out + (long)(c0 + c) * DD + r0 + r8 * 8) = *(s8v*)vals;
  }
}

// ---------------------------------------------------------------------------
// Fused QKV projection GEMM v2: C = Xb @ W + bias. Xb bf16 (A direct from
// global/L2); WT staged via global_load_lds into chunk-major LDS.
// Q,K head-split [bh][s][d]; V TRANSPOSED [bh][d][s]. Q pre-scaled by SCALEQ.
// grid (8 n, 32 m, 3 z), block 256.
__global__ __launch_bounds__(256, 3) void proj_gemm(
    const unsigned short* __restrict__ Xb, const unsigned short* __restrict__ WTbase,
    const float* __restrict__ bq, const float* __restrict__ bk,
    const float* __restrict__ bv,
    unsigned short* __restrict__ qbuf, unsigned short* __restrict__ kbuf,
    unsigned short* __restrict__ vTbuf) {
  __shared__ __align__(16) unsigned short wt[8][128][8];  // [k-chunk][n][8k] 16KB
  const int z = blockIdx.z;
  const unsigned short* X = Xb + (long)z * 4096 * DD;
  const unsigned short* WT = WTbase + (long)z * DD * DD;
  const float* bias = (z == 0) ? bq : (z == 1) ? bk : bv;
  const float osc = (z == 0) ? SCALEQ : 1.0f;

  const int n0 = blockIdx.x * 128, m0 = blockIdx.y * 128;
  const int t = threadIdx.x, w = t >> 6, l = t & 63;
  const int lm = l & 15, qd = l >> 4;

  f4 acc[8][2];
  #pragma unroll
  for (int i = 0; i < 8; ++i) { acc[i][0] = (f4)0.0f; acc[i][1] = (f4)0.0f; }

  const unsigned short* x0 = X + (long)(m0 + w * 32 + lm) * DD;
  const unsigned short* x1 = x0 + 16 * DD;

  for (int k0 = 0; k0 < DD; k0 += 64) {
    __syncthreads();   // all waves done reading wt from previous iter
    // stage WT tile [128 n][64 k] chunk-major via DMA: 4 issues per wave
    #pragma unroll
    for (int i = 0; i < 4; ++i) {
      int idx = w * 4 + i;            // 0..15
      int c = idx >> 1, hh = (idx & 1) * 64;
      gl_lds16(WT + (long)(n0 + hh + l) * DD + k0 + c * 8, &wt[c][hh][0]);
    }
    // A fragments direct from bf16 global (L2-served)
    s8v a00 = *(const s8v*)(x0 + k0 + qd * 8);
    s8v a01 = *(const s8v*)(x0 + k0 + 32 + qd * 8);
    s8v a10 = *(const s8v*)(x1 + k0 + qd * 8);
    s8v a11 = *(const s8v*)(x1 + k0 + 32 + qd * 8);
    asm volatile("s_waitcnt vmcnt(0)" ::: "memory");
    __syncthreads();   // DMA landed for all waves
    #pragma unroll
    for (int cb = 0; cb < 8; ++cb) {
      s8v b0 = *(const s8v*)&wt[qd][cb * 16 + lm][0];
      s8v b1 = *(const s8v*)&wt[4 + qd][cb * 16 + lm][0];
      acc[cb][0] = MFMA_BF16(a00, b0, acc[cb][0], 0, 0, 0);
      acc[cb][0] = MFMA_BF16(a01, b1, acc[cb][0], 0, 0, 0);
      acc[cb][1] = MFMA_BF16(a10, b0, acc[cb][1], 0, 0, 0);
      acc[cb][1] = MFMA_BF16(a11, b1, acc[cb][1], 0, 0, 0);
    }
  }
  if (z == 2) {
    // V: write transposed [bh][d][s], 8B vector stores (r -> s contiguous)
    #pragma unroll
    for (int cb = 0; cb < 8; ++cb) {
      int n = n0 + cb * 16 + lm;
      float bvv = bias[n];
      int hh = n >> 6, d = n & 63;
      #pragma unroll
      for (int ms = 0; ms < 2; ++ms) {
        int m = m0 + w * 32 + ms * 16 + qd * 4;
        int bidx = m >> 11, s = m & (SS - 1);
        unsigned short o4[4];
        #pragma unroll
        for (int r = 0; r < 4; ++r) o4[r] = f2bf(acc[cb][ms][r] + bvv);
        *(s4v*)&vTbuf[((long)(bidx * HH + hh) * HD + d) * SS + s] = *(s4v*)o4;
      }
    }
  } else {
    unsigned short* out = (z == 0) ? qbuf : kbuf;
    #pragma unroll
    for (int cb = 0; cb < 8; ++cb) {
      int n = n0 + cb * 16 + lm;
      float bvv = bias[n];
      int hh = n >> 6, d = n & 63;
      #pragma unroll
      for (int ms = 0; ms < 2; ++ms) {
        #pragma unroll
        for (int r = 0; r < 4; ++r) {
          int m = m0 + w * 32 + ms * 16 + qd * 4 + r;
          int bidx = m >> 11, s = m & (SS - 1);
          out[((long)(bidx * HH + hh) * SS + s) * HD + d] = f2bf((acc[cb][ms][r] + bvv) * osc);
        }
      }
    }
  }
}

// ---------------------------------------------------------------------------
// Flash attention, S-transposed, double-buffered global_load_lds K/V staging
// shared by all 4 waves. 64 keys per round, 32 rounds. (unchanged from R7)
// grid (32 q-blocks, 32 bh), block 256.
__global__ __launch_bounds__(256, 2) void attn(
    const unsigned short* __restrict__ qb, const unsigned short* __restrict__ kb,
    const unsigned short* __restrict__ vt, const float* __restrict__ tableF,
    const float* __restrict__ maskF, float* __restrict__ out) {
  __shared__ __align__(16) unsigned short ks[2][8][64][8];  // [buf][d-chunk][key][8d]
  __shared__ __align__(16) unsigned short vs[2][8][64][8];  // [buf][k-chunk][d][8k]
  __shared__ __align__(16) unsigned short qr2[NREL][66];    // [dist][q_local]
  __shared__ __align__(16) unsigned short pbuf[4][16][40];  // per-wave P, 2-phase
  __shared__ float mk[SS];                                  // mask*LOG2E

  const int bh = blockIdx.y, b = bh >> 4, h = bh & 15;
  const int q0 = blockIdx.x * 64;
  const int t = threadIdx.x, w = t >> 6, l = t & 63;
  const int lm = l & 15, qd = l >> 4;

  const unsigned short* kkb = kb + (long)bh * SS * HD;
  const unsigned short* vvb = vt + (long)bh * HD * SS;
  const int c0s = 2 * w, c1s = c0s + 1;

  // stage round 0 (keys 0..63) into buf 0
  gl_lds16(kkb + (long)l * HD + c0s * 8, &ks[0][c0s][0][0]);
  gl_lds16(kkb + (long)l * HD + c1s * 8, &ks[0][c1s][0][0]);
  gl_lds16(vvb + (long)l * SS + c0s * 8, &vs[0][c0s][0][0]);
  gl_lds16(vvb + (long)l * SS + c1s * 8, &vs[0][c1s][0][0]);

  // stage mask (pre-scaled by LOG2E)
  {
    const float* mrow = maskF + b * SS;
    f4 m0v = *(const f4*)(mrow + t * 8);
    f4 m1v = *(const f4*)(mrow + t * 8 + 4);
    #pragma unroll
    for (int e = 0; e < 4; ++e) {
      mk[t * 8 + e] = m0v[e] * LOG2E;
      mk[t * 8 + 4 + e] = m1v[e] * LOG2E;
    }
  }

  // Q fragments (q = q0 + w*16 + lm), pre-scaled by SCALEQ
  const unsigned short* qrow = qb + ((long)bh * SS + q0 + w * 16 + lm) * HD;
  const s8v qa0 = *(const s8v*)(qrow + qd * 8);
  const s8v qa1 = *(const s8v*)(qrow + 32 + qd * 8);

  // Fused qrel: qr2[dist][q_local] = q_scaled . table[dist]
  #pragma unroll
  for (int cb = 0; cb < 9; ++cb) {
    int dist = cb * 16 + lm;
    int dc = dist > NREL - 1 ? NREL - 1 : dist;
    const float* trow = tableF + dc * HD;
    f4 t0 = *(const f4*)(trow + qd * 8);
    f4 t1 = *(const f4*)(trow + qd * 8 + 4);
    f4 t2 = *(const f4*)(trow + 32 + qd * 8);
    f4 t3 = *(const f4*)(trow + 32 + qd * 8 + 4);
    unsigned int tb[8];
    tb[0] = pk2bf(t0[0], t0[1]); tb[1] = pk2bf(t0[2], t0[3]);
    tb[2] = pk2bf(t1[0], t1[1]); tb[3] = pk2bf(t1[2], t1[3]);
    tb[4] = pk2bf(t2[0], t2[1]); tb[5] = pk2bf(t2[2], t2[3]);
    tb[6] = pk2bf(t3[0], t3[1]); tb[7] = pk2bf(t3[2], t3[3]);
    s8v b0 = *(s8v*)tb, b1 = *(s8v*)(tb + 4);
    f4 c = MFMA_BF16(qa0, b0, (f4)0.0f, 0, 0, 0);
    c = MFMA_BF16(qa1, b1, c, 0, 0, 0);
    if (dist <= NREL - 1) {
      #pragma unroll
      for (int r = 0; r < 4; ++r)
        qr2[dist][w * 16 + qd * 4 + r] = f2bf(c[r]);
    }
  }
  asm volatile("s_waitcnt vmcnt(0)" ::: "memory");
  __syncthreads();

  const int qcol = w * 16 + lm;
  const float bLo = bf2f(qr2[0][qcol]);
  const float bHi = bf2f(qr2[128][qcol]);

  float m_ = -1e30f, l_ = 0.0f;
  f4 c4[4];
  #pragma unroll
  for (int i = 0; i < 4; ++i) c4[i] = (f4)0.0f;

  for (int rr = 0; rr < 32; ++rr) {
    const int kk = rr << 6;
    const int buf = rr & 1;
    if (rr < 31) {
      const int nb = buf ^ 1;
      const long kof = kk + 64;
      gl_lds16(kkb + (kof + l) * HD + c0s * 8, &ks[nb][c0s][0][0]);
      gl_lds16(kkb + (kof + l) * HD + c1s * 8, &ks[nb][c1s][0][0]);
      gl_lds16(vvb + (long)l * SS + kof + c0s * 8, &vs[nb][c0s][0][0]);
      gl_lds16(vvb + (long)l * SS + kof + c1s * 8, &vs[nb][c1s][0][0]);
    }
    f4 st[4];
    #pragma unroll
    for (int tt = 0; tt < 4; ++tt) {
      s8v k0v = *(const s8v*)&ks[buf][qd][tt * 16 + lm][0];
      s8v k1v = *(const s8v*)&ks[buf][4 + qd][tt * 16 + lm][0];
      st[tt] = MFMA_BF16(k0v, qa0, (f4)0.0f, 0, 0, 0);
      st[tt] = MFMA_BF16(k1v, qa1, st[tt], 0, 0, 0);
    }
    float z[16];
    const int kband = kk - q0;
    if (kband >= 128) {
      #pragma unroll
      for (int tt = 0; tt < 4; ++tt) {
        f4 mv = *(const f4*)&mk[kk + tt * 16 + qd * 4];
        #pragma unroll
        for (int r = 0; r < 4; ++r) z[tt * 4 + r] = st[tt][r] + bHi + mv[r];
      }
    } else if (kband <= -128) {
      #pragma unroll
      for (int tt = 0; tt < 4; ++tt) {
        f4 mv = *(const f4*)&mk[kk + tt * 16 + qd * 4];
        #pragma unroll
        for (int r = 0; r < 4; ++r) z[tt * 4 + r] = st[tt][r] + bLo + mv[r];
      }
    } else {
      const int dbb = kband - qcol + 64 + qd * 4;
      #pragma unroll
      for (int tt = 0; tt < 4; ++tt) {
        f4 mv = *(const f4*)&mk[kk + tt * 16 + qd * 4];
        #pragma unroll
        for (int r = 0; r < 4; ++r) {
          int d = dbb + tt * 16 + r;
          d = d < 0 ? 0 : (d > 128 ? 128 : d);
          z[tt * 4 + r] = st[tt][r] + bf2f(qr2[d][qcol]) + mv[r];
        }
      }
    }
    float tm = z[0];
    #pragma unroll
    for (int i = 1; i < 16; ++i) tm = fmaxf(tm, z[i]);
    tm = fmaxf(tm, __shfl_xor(tm, 16));
    tm = fmaxf(tm, __shfl_xor(tm, 32));
    float mn = fmaxf(m_, tm);
    float alpha = __builtin_amdgcn_exp2f(m_ - mn);
    m_ = mn;
    float p[16];
    #pragma unroll
    for (int i = 0; i < 16; ++i) p[i] = __builtin_amdgcn_exp2f(z[i] - mn);
    float ts = 0.0f;
    #pragma unroll
    for (int i = 0; i < 16; ++i) ts += p[i];
    ts += __shfl_xor(ts, 16);
    ts += __shfl_xor(ts, 32);
    l_ = l_ * alpha + ts;
    #pragma unroll
    for (int db = 0; db < 4; ++db)
      #pragma unroll
      for (int r = 0; r < 4; ++r) c4[db][r] *= alpha;

    *(unsigned int*)&pbuf[w][lm][qd * 4] = pk2bf(p[0], p[1]);
    *(unsigned int*)&pbuf[w][lm][qd * 4 + 2] = pk2bf(p[2], p[3]);
    *(unsigned int*)&pbuf[w][lm][16 + qd * 4] = pk2bf(p[4], p[5]);
    *(unsigned int*)&pbuf[w][lm][16 + qd * 4 + 2] = pk2bf(p[6], p[7]);
    asm volatile("s_waitcnt lgkmcnt(0)" ::: "memory");
    {
      s8v pa = *(const s8v*)&pbuf[w][lm][qd * 8];
      #pragma unroll
      for (int db = 0; db < 4; ++db) {
        s8v va = *(const s8v*)&vs[buf][qd][db * 16 + lm][0];
        c4[db] = MFMA_BF16(va, pa, c4[db], 0, 0, 0);
      }
    }
    *(unsigned int*)&pbuf[w][lm][qd * 4] = pk2bf(p[8], p[9]);
    *(unsigned int*)&pbuf[w][lm][qd * 4 + 2] = pk2bf(p[10], p[11]);
    *(unsigned int*)&pbuf[w][lm][16 + qd * 4] = pk2bf(p[12], p[13]);
    *(unsigned int*)&pbuf[w][lm][16 + qd * 4 + 2] = pk2bf(p[14], p[15]);
    asm volatile("s_waitcnt lgkmcnt(0)" ::: "memory");
    {
      s8v pb = *(const s8v*)&pbuf[w][lm][qd * 8];
      #pragma unroll
      for (int db = 0; db < 4; ++db) {
        s8v vb = *(const s8v*)&vs[buf][4 + qd][db * 16 + lm][0];
        c4[db] = MFMA_BF16(vb, pb, c4[db], 0, 0, 0);
      }
    }
    asm volatile("s_waitcnt vmcnt(0)" ::: "memory");
    __syncthreads();
  }

  const float inv = 1.0f / l_;
  float* obase = out + ((long)b * SS + q0 + qcol) * DD + h * HD;
  #pragma unroll
  for (int db = 0; db < 4; ++db) {
    f4 o;
    #pragma unroll
    for (int r = 0; r < 4; ++r) o[r] = c4[db][r] * inv;
    *(f4*)(obase + db * 16 + qd * 4) = o;
  }
}

// ---------------------------------------------------------------------------
extern "C" void kernel_launch(void* const* d_in, const int* in_sizes, int n_in,
                              void* d_out, int out_size, void* d_ws, size_t ws_size,
                              hipStream_t stream) {
  const float* query = (const float*)d_in[0];
  const float* key   = (const float*)d_in[1];
  const float* value = (const float*)d_in[2];
  const float* mask  = (const float*)d_in[3];
  const float* Wq    = (const float*)d_in[4];
  const float* bq    = (const float*)d_in[5];
  const float* Wk    = (const float*)d_in[6];
  const float* bk    = (const float*)d_in[7];
  const float* Wv    = (const float*)d_in[8];
  const float* bv    = (const float*)d_in[9];
  const float* table = (const float*)d_in[10];

  char* ws = (char*)d_ws;
  // workspace layout (bytes), span 56 MB
  unsigned short* WT   = (unsigned short*)(ws);               // 6,291,456
  unsigned short* Xb   = (unsigned short*)(ws + (8l << 20));  // 25,165,824
  unsigned short* qbuf = (unsigned short*)(ws + (32l << 20));
  unsigned short* kbuf = (unsigned short*)(ws + (40l << 20));
  unsigned short* vT   = (unsigned short*)(ws + (48l << 20));

  // 1) convert inputs fp32 -> bf16 (once)
  cvt_x<<<dim3(2048, 3, 1), 256, 0, stream>>>(query, key, value, Xb);

  // 2) transpose+convert weights: WT[z][n][k] = W[z][k][n]
  cvt_w<<<dim3(16, 16, 3), 256, 0, stream>>>(Wq, Wk, Wv, WT);

  // 3) fused QKV projections; V written pre-transposed [bh][d][s]
  proj_gemm<<<dim3(8, 32, 3), 256, 0, stream>>>(Xb, WT, bq, bk, bv,
                                                qbuf, kbuf, vT);

  // 4) flash attention (S-transposed, LDS-staged K/V), fp32 output
  attn<<<dim3(32, 32, 1), 256, 0, stream>>>(qbuf, kbuf, vT, table, mask,
                                            (float*)d_out);
}

// Round 9
// 258.805 us; speedup vs baseline: 1.7024x; 1.1025x over previous
//
#include <hip/hip_runtime.h>
#include <hip/hip_bf16.h>

// Problem constants
#define BB 2
#define SS 2048
#define DD 1024
#define HH 16
#define HD 64
#define NREL 129
#define LOG2E 1.4426950408889634f
#define SCALEQ (LOG2E / 8.0f)   // folded into Q at projection time
#define KVB 131072l              // elems per bh in ktile/vtile (32*8*64*8)

typedef short s8v __attribute__((ext_vector_type(8)));
typedef short s4v __attribute__((ext_vector_type(4)));
typedef float f4 __attribute__((ext_vector_type(4)));

#define MFMA_BF16 __builtin_amdgcn_mfma_f32_16x16x32_bf16

__device__ __forceinline__ float bf2f(unsigned short u) {
  union { unsigned int i; float f; } x; x.i = ((unsigned int)u) << 16; return x.f;
}
__device__ __forceinline__ unsigned short f2bf(float f) {
  union { float f; unsigned int i; } x; x.f = f;
  unsigned int r = x.i + 0x7fffu + ((x.i >> 16) & 1u);
  return (unsigned short)(r >> 16);
}
__device__ __forceinline__ unsigned int pk2bf(float a, float b) {
  union { __hip_bfloat162 h2; unsigned int u; } c;
  c.h2 = __float22bfloat162_rn(float2{a, b});
  return c.u;
}
// async global->LDS DMA, 16B/lane; global src MUST be lane-contiguous for
// coalescing (tiled layouts below guarantee it); LDS dest = base + lane*16
__device__ __forceinline__ void gl_lds16(const void* g, void* l) {
  __builtin_amdgcn_global_load_lds(
      (const __attribute__((address_space(1))) unsigned int*)g,
      (__attribute__((address_space(3))) unsigned int*)l, 16, 0, 0);
}

// ---------------------------------------------------------------------------
// fp32 -> bf16 convert of the 3 input tensors [4096][1024] -> xb [3][4096*1024]
__global__ __launch_bounds__(256) void cvt_x(
    const float* __restrict__ xq, const float* __restrict__ xk,
    const float* __restrict__ xv, unsigned short* __restrict__ xb) {
  const int z = blockIdx.y;
  const float* in = (z == 0) ? xq : (z == 1) ? xk : xv;
  unsigned short* out = xb + (long)z * 4096 * DD;
  const long i = ((long)blockIdx.x * 256 + threadIdx.x) * 8;
  f4 a = *(const f4*)(in + i);
  f4 b = *(const f4*)(in + i + 4);
  unsigned int u[4];
  u[0] = pk2bf(a[0], a[1]); u[1] = pk2bf(a[2], a[3]);
  u[2] = pk2bf(b[0], b[1]); u[3] = pk2bf(b[2], b[3]);
  *(s8v*)(out + i) = *(s8v*)u;
}

// ---------------------------------------------------------------------------
// Weight transpose+convert to TILED layout:
// WTt[z][n0g(8)][k0g(16)][kc(8)][n(128)][8k] — 16 KB per (n0,k0) tile,
// byte-image of proj_gemm's LDS tile. grid (16, 16, 3), block 256.
__global__ __launch_bounds__(256) void cvt_w(
    const float* __restrict__ Wq, const float* __restrict__ Wk,
    const float* __restrict__ Wv, unsigned short* __restrict__ WTt) {
  __shared__ unsigned short tile[64][72];
  const int z = blockIdx.z;
  const float* in = (z == 0) ? Wq : (z == 1) ? Wk : Wv;
  unsigned short* out = WTt + (long)z * 1048576;
  const int c0 = blockIdx.x * 64, r0 = blockIdx.y * 64;  // c0: n-base, r0: k-base
  const int t = threadIdx.x;
  const int r = t >> 2;
  #pragma unroll
  for (int j = 0; j < 4; ++j) {
    int cc = (t & 3) * 16 + j * 4;
    f4 v = *(const f4*)(in + (long)(r0 + r) * DD + c0 + cc);
    #pragma unroll
    for (int e = 0; e < 4; ++e) tile[r][cc + e] = f2bf(v[e]);
  }
  __syncthreads();
  const int c = t >> 2;           // n within 64-tile
  #pragma unroll
  for (int h = 0; h < 2; ++h) {
    int r8 = (t & 3) + 4 * h;     // k-octet within 64-tile
    unsigned short vals[8];
    #pragma unroll
    for (int j = 0; j < 8; ++j) vals[j] = tile[r8 * 8 + j][c];
    int n = c0 + c, kb = r0 + r8 * 8;
    long off = ((long)(n >> 7) * 131072) + ((kb >> 6) * 8192) +
               (((kb & 63) >> 3) * 1024) + ((n & 127) * 8);
    *(s8v*)(out + off) = *(s8v*)vals;
  }
}

// ---------------------------------------------------------------------------
// Fused QKV projection GEMM: C = Xb @ W + bias.
// Q head-split [bh][s][d] (pre-scaled); K -> ktile[bh][g][c][key][8];
// V -> vtile[bh][g][c][d][8] (tiled byte-images of attn's LDS buffers).
// WT staged via coalesced gl_lds16 from WTt. grid (8 n, 32 m, 3 z), block 256.
__global__ __launch_bounds__(256, 4) void proj_gemm(
    const unsigned short* __restrict__ Xb, const unsigned short* __restrict__ WTt,
    const float* __restrict__ bq, const float* __restrict__ bk,
    const float* __restrict__ bv,
    unsigned short* __restrict__ qbuf, unsigned short* __restrict__ ktile,
    unsigned short* __restrict__ vtile) {
  __shared__ __align__(16) unsigned short wt[8][128][8];  // [kc][n][8k] 16KB
  unsigned short* wtf = &wt[0][0][0];
  const int z = blockIdx.z;
  const unsigned short* X = Xb + (long)z * 4096 * DD;
  const unsigned short* WTz = WTt + (long)z * 1048576;
  const float* bias = (z == 0) ? bq : (z == 1) ? bk : bv;

  const int n0 = blockIdx.x * 128, m0 = blockIdx.y * 128;
  const int t = threadIdx.x, w = t >> 6, l = t & 63;
  const int lm = l & 15, qd = l >> 4;

  f4 acc[8][2];
  #pragma unroll
  for (int i = 0; i < 8; ++i) { acc[i][0] = (f4)0.0f; acc[i][1] = (f4)0.0f; }

  const unsigned short* x0 = X + (long)(m0 + w * 32 + lm) * DD;
  const unsigned short* x1 = x0 + 16 * DD;
  const unsigned short* wtile0 = WTz + (long)(n0 >> 7) * 131072;

  for (int k0 = 0; k0 < DD; k0 += 64) {
    __syncthreads();   // all waves done reading wt from previous iter
    // stage 16 KB WT tile: 16 lane-contiguous 1KB DMA bursts
    const unsigned short* tb = wtile0 + (k0 >> 6) * 8192;
    #pragma unroll
    for (int i = 0; i < 4; ++i) {
      int idx = w * 4 + i;
      gl_lds16(tb + idx * 512 + l * 8, wtf + idx * 512);
    }
    // A fragments direct from bf16 global (L2-served)
    s8v a00 = *(const s8v*)(x0 + k0 + qd * 8);
    s8v a01 = *(const s8v*)(x0 + k0 + 32 + qd * 8);
    s8v a10 = *(const s8v*)(x1 + k0 + qd * 8);
    s8v a11 = *(const s8v*)(x1 + k0 + 32 + qd * 8);
    asm volatile("s_waitcnt vmcnt(0)" ::: "memory");
    __syncthreads();   // DMA landed for all waves
    #pragma unroll
    for (int cb = 0; cb < 8; ++cb) {
      s8v b0 = *(const s8v*)&wt[qd][cb * 16 + lm][0];
      s8v b1 = *(const s8v*)&wt[4 + qd][cb * 16 + lm][0];
      acc[cb][0] = MFMA_BF16(a00, b0, acc[cb][0], 0, 0, 0);
      acc[cb][0] = MFMA_BF16(a01, b1, acc[cb][0], 0, 0, 0);
      acc[cb][1] = MFMA_BF16(a10, b0, acc[cb][1], 0, 0, 0);
      acc[cb][1] = MFMA_BF16(a11, b1, acc[cb][1], 0, 0, 0);
    }
  }
  if (z == 0) {
    // Q: head-split [bh][s][d], pre-scaled
    #pragma unroll
    for (int cb = 0; cb < 8; ++cb) {
      int n = n0 + cb * 16 + lm;
      float bvv = bias[n];
      int hh = n >> 6, d = n & 63;
      #pragma unroll
      for (int ms = 0; ms < 2; ++ms) {
        #pragma unroll
        for (int r = 0; r < 4; ++r) {
          int m = m0 + w * 32 + ms * 16 + qd * 4 + r;
          int bidx = m >> 11, s = m & (SS - 1);
          qbuf[((long)(bidx * HH + hh) * SS + s) * HD + d] =
              f2bf((acc[cb][ms][r] + bvv) * SCALEQ);
        }
      }
    }
  } else if (z == 1) {
    // K -> ktile[bh][g][c][key][8]
    #pragma unroll
    for (int cb = 0; cb < 8; ++cb) {
      int n = n0 + cb * 16 + lm;
      float bvv = bias[n];
      int hh = n >> 6, d = n & 63;
      int c = d >> 3, e = d & 7;
      #pragma unroll
      for (int ms = 0; ms < 2; ++ms) {
        #pragma unroll
        for (int r = 0; r < 4; ++r) {
          int m = m0 + w * 32 + ms * 16 + qd * 4 + r;
          int bidx = m >> 11, s = m & (SS - 1);
          long bh = bidx * HH + hh;
          ktile[bh * KVB + (s >> 6) * 4096 + c * 512 + (s & 63) * 8 + e] =
              f2bf(acc[cb][ms][r] + bvv);
        }
      }
    }
  } else {
    // V -> vtile[bh][g][c][d][8], 4 consecutive s per 8B store
    #pragma unroll
    for (int cb = 0; cb < 8; ++cb) {
      int n = n0 + cb * 16 + lm;
      float bvv = bias[n];
      int hh = n >> 6, d = n & 63;
      #pragma unroll
      for (int ms = 0; ms < 2; ++ms) {
        int m = m0 + w * 32 + ms * 16 + qd * 4;
        int bidx = m >> 11, s = m & (SS - 1);
        long bh = bidx * HH + hh;
        unsigned short o4[4];
        #pragma unroll
        for (int r = 0; r < 4; ++r) o4[r] = f2bf(acc[cb][ms][r] + bvv);
        *(s4v*)&vtile[bh * KVB + (s >> 6) * 4096 + ((s & 63) >> 3) * 512 +
                      d * 8 + (s & 7)] = *(s4v*)o4;
      }
    }
  }
}

// ---------------------------------------------------------------------------
// Flash attention, S-transposed, double-buffered coalesced DMA K/V staging.
// grid (32 q-blocks, 32 bh), block 256.
__global__ __launch_bounds__(256, 2) void attn(
    const unsigned short* __restrict__ qb, const unsigned short* __restrict__ ktile,
    const unsigned short* __restrict__ vtile, const float* __restrict__ tableF,
    const float* __restrict__ maskF, float* __restrict__ out) {
  __shared__ __align__(16) unsigned short ks[2][8][64][8];  // [buf][d-chunk][key][8d]
  __shared__ __align__(16) unsigned short vs[2][8][64][8];  // [buf][k-chunk][d][8k]
  __shared__ __align__(16) unsigned short qr2[NREL][66];    // [dist][q_local]
  __shared__ __align__(16) unsigned short pbuf[4][16][40];  // per-wave P, 2-phase
  __shared__ float mk[SS];                                  // mask*LOG2E

  const int bh = blockIdx.y, b = bh >> 4, h = bh & 15;
  const int q0 = blockIdx.x * 64;
  const int t = threadIdx.x, w = t >> 6, l = t & 63;
  const int lm = l & 15, qd = l >> 4;

  const unsigned short* kkb = ktile + (long)bh * KVB;
  const unsigned short* vvb = vtile + (long)bh * KVB;

  // stage round 0 (key-group 0) into buf 0: lane-contiguous 1KB bursts
  #pragma unroll
  for (int i = 0; i < 2; ++i) {
    int c = 2 * w + i;
    gl_lds16(kkb + c * 512 + l * 8, &ks[0][c][0][0]);
    gl_lds16(vvb + c * 512 + l * 8, &vs[0][c][0][0]);
  }

  // stage mask (pre-scaled by LOG2E)
  {
    const float* mrow = maskF + b * SS;
    f4 m0v = *(const f4*)(mrow + t * 8);
    f4 m1v = *(const f4*)(mrow + t * 8 + 4);
    #pragma unroll
    for (int e = 0; e < 4; ++e) {
      mk[t * 8 + e] = m0v[e] * LOG2E;
      mk[t * 8 + 4 + e] = m1v[e] * LOG2E;
    }
  }

  // Q fragments (q = q0 + w*16 + lm), pre-scaled by SCALEQ
  const unsigned short* qrow = qb + ((long)bh * SS + q0 + w * 16 + lm) * HD;
  const s8v qa0 = *(const s8v*)(qrow + qd * 8);
  const s8v qa1 = *(const s8v*)(qrow + 32 + qd * 8);

  // Fused qrel: qr2[dist][q_local] = q_scaled . table[dist]
  #pragma unroll
  for (int cb = 0; cb < 9; ++cb) {
    int dist = cb * 16 + lm;
    int dc = dist > NREL - 1 ? NREL - 1 : dist;
    const float* trow = tableF + dc * HD;
    f4 t0 = *(const f4*)(trow + qd * 8);
    f4 t1 = *(const f4*)(trow + qd * 8 + 4);
    f4 t2 = *(const f4*)(trow + 32 + qd * 8);
    f4 t3 = *(const f4*)(trow + 32 + qd * 8 + 4);
    unsigned int tb[8];
    tb[0] = pk2bf(t0[0], t0[1]); tb[1] = pk2bf(t0[2], t0[3]);
    tb[2] = pk2bf(t1[0], t1[1]); tb[3] = pk2bf(t1[2], t1[3]);
    tb[4] = pk2bf(t2[0], t2[1]); tb[5] = pk2bf(t2[2], t2[3]);
    tb[6] = pk2bf(t3[0], t3[1]); tb[7] = pk2bf(t3[2], t3[3]);
    s8v b0 = *(s8v*)tb, b1 = *(s8v*)(tb + 4);
    f4 c = MFMA_BF16(qa0, b0, (f4)0.0f, 0, 0, 0);
    c = MFMA_BF16(qa1, b1, c, 0, 0, 0);
    if (dist <= NREL - 1) {
      #pragma unroll
      for (int r = 0; r < 4; ++r)
        qr2[dist][w * 16 + qd * 4 + r] = f2bf(c[r]);
    }
  }
  asm volatile("s_waitcnt vmcnt(0)" ::: "memory");
  __syncthreads();

  const int qcol = w * 16 + lm;
  const float bLo = bf2f(qr2[0][qcol]);
  const float bHi = bf2f(qr2[128][qcol]);

  float m_ = -1e30f, l_ = 0.0f;
  f4 c4[4];
  #pragma unroll
  for (int i = 0; i < 4; ++i) c4[i] = (f4)0.0f;

  for (int rr = 0; rr < 32; ++rr) {
    const int kk = rr << 6;
    const int buf = rr & 1;
    if (rr < 31) {
      const int nb = buf ^ 1;
      const unsigned short* kg = kkb + (rr + 1) * 4096;
      const unsigned short* vg = vvb + (rr + 1) * 4096;
      #pragma unroll
      for (int i = 0; i < 2; ++i) {
        int c = 2 * w + i;
        gl_lds16(kg + c * 512 + l * 8, &ks[nb][c][0][0]);
        gl_lds16(vg + c * 512 + l * 8, &vs[nb][c][0][0]);
      }
    }
    f4 st[4];
    #pragma unroll
    for (int tt = 0; tt < 4; ++tt) {
      s8v k0v = *(const s8v*)&ks[buf][qd][tt * 16 + lm][0];
      s8v k1v = *(const s8v*)&ks[buf][4 + qd][tt * 16 + lm][0];
      st[tt] = MFMA_BF16(k0v, qa0, (f4)0.0f, 0, 0, 0);
      st[tt] = MFMA_BF16(k1v, qa1, st[tt], 0, 0, 0);
    }
    float z[16];
    const int kband = kk - q0;
    if (kband >= 128) {
      #pragma unroll
      for (int tt = 0; tt < 4; ++tt) {
        f4 mv = *(const f4*)&mk[kk + tt * 16 + qd * 4];
        #pragma unroll
        for (int r = 0; r < 4; ++r) z[tt * 4 + r] = st[tt][r] + bHi + mv[r];
      }
    } else if (kband <= -128) {
      #pragma unroll
      for (int tt = 0; tt < 4; ++tt) {
        f4 mv = *(const f4*)&mk[kk + tt * 16 + qd * 4];
        #pragma unroll
        for (int r = 0; r < 4; ++r) z[tt * 4 + r] = st[tt][r] + bLo + mv[r];
      }
    } else {
      const int dbb = kband - qcol + 64 + qd * 4;
      #pragma unroll
      for (int tt = 0; tt < 4; ++tt) {
        f4 mv = *(const f4*)&mk[kk + tt * 16 + qd * 4];
        #pragma unroll
        for (int r = 0; r < 4; ++r) {
          int d = dbb + tt * 16 + r;
          d = d < 0 ? 0 : (d > 128 ? 128 : d);
          z[tt * 4 + r] = st[tt][r] + bf2f(qr2[d][qcol]) + mv[r];
        }
      }
    }
    float tm = z[0];
    #pragma unroll
    for (int i = 1; i < 16; ++i) tm = fmaxf(tm, z[i]);
    tm = fmaxf(tm, __shfl_xor(tm, 16));
    tm = fmaxf(tm, __shfl_xor(tm, 32));
    float mn = fmaxf(m_, tm);
    float alpha = __builtin_amdgcn_exp2f(m_ - mn);
    m_ = mn;
    float p[16];
    #pragma unroll
    for (int i = 0; i < 16; ++i) p[i] = __builtin_amdgcn_exp2f(z[i] - mn);
    float ts = 0.0f;
    #pragma unroll
    for (int i = 0; i < 16; ++i) ts += p[i];
    ts += __shfl_xor(ts, 16);
    ts += __shfl_xor(ts, 32);
    l_ = l_ * alpha + ts;
    #pragma unroll
    for (int db = 0; db < 4; ++db)
      #pragma unroll
      for (int r = 0; r < 4; ++r) c4[db][r] *= alpha;

    *(unsigned int*)&pbuf[w][lm][qd * 4] = pk2bf(p[0], p[1]);
    *(unsigned int*)&pbuf[w][lm][qd * 4 + 2] = pk2bf(p[2], p[3]);
    *(unsigned int*)&pbuf[w][lm][16 + qd * 4] = pk2bf(p[4], p[5]);
    *(unsigned int*)&pbuf[w][lm][16 + qd * 4 + 2] = pk2bf(p[6], p[7]);
    asm volatile("s_waitcnt lgkmcnt(0)" ::: "memory");
    {
      s8v pa = *(const s8v*)&pbuf[w][lm][qd * 8];
      #pragma unroll
      for (int db = 0; db < 4; ++db) {
        s8v va = *(const s8v*)&vs[buf][qd][db * 16 + lm][0];
        c4[db] = MFMA_BF16(va, pa, c4[db], 0, 0, 0);
      }
    }
    *(unsigned int*)&pbuf[w][lm][qd * 4] = pk2bf(p[8], p[9]);
    *(unsigned int*)&pbuf[w][lm][qd * 4 + 2] = pk2bf(p[10], p[11]);
    *(unsigned int*)&pbuf[w][lm][16 + qd * 4] = pk2bf(p[12], p[13]);
    *(unsigned int*)&pbuf[w][lm][16 + qd * 4 + 2] = pk2bf(p[14], p[15]);
    asm volatile("s_waitcnt lgkmcnt(0)" ::: "memory");
    {
      s8v pb = *(const s8v*)&pbuf[w][lm][qd * 8];
      #pragma unroll
      for (int db = 0; db < 4; ++db) {
        s8v vb = *(const s8v*)&vs[buf][4 + qd][db * 16 + lm][0];
        c4[db] = MFMA_BF16(vb, pb, c4[db], 0, 0, 0);
      }
    }
    asm volatile("s_waitcnt vmcnt(0)" ::: "memory");
    __syncthreads();
  }

  const float inv = 1.0f / l_;
  float* obase = out + ((long)b * SS + q0 + qcol) * DD + h * HD;
  #pragma unroll
  for (int db = 0; db < 4; ++db) {
    f4 o;
    #pragma unroll
    for (int r = 0; r < 4; ++r) o[r] = c4[db][r] * inv;
    *(f4*)(obase + db * 16 + qd * 4) = o;
  }
}

// ---------------------------------------------------------------------------
extern "C" void kernel_launch(void* const* d_in, const int* in_sizes, int n_in,
                              void* d_out, int out_size, void* d_ws, size_t ws_size,
                              hipStream_t stream) {
  const float* query = (const float*)d_in[0];
  const float* key   = (const float*)d_in[1];
  const float* value = (const float*)d_in[2];
  const float* mask  = (const float*)d_in[3];
  const float* Wq    = (const float*)d_in[4];
  const float* bq    = (const float*)d_in[5];
  const float* Wk    = (const float*)d_in[6];
  const float* bk    = (const float*)d_in[7];
  const float* Wv    = (const float*)d_in[8];
  const float* bv    = (const float*)d_in[9];
  const float* table = (const float*)d_in[10];

  char* ws = (char*)d_ws;
  // workspace layout (bytes), span 56 MB
  unsigned short* WTt   = (unsigned short*)(ws);               // 6,291,456 (tiled)
  unsigned short* Xb    = (unsigned short*)(ws + (8l << 20));  // 25,165,824
  unsigned short* qbuf  = (unsigned short*)(ws + (32l << 20));
  unsigned short* ktile = (unsigned short*)(ws + (40l << 20));
  unsigned short* vtile = (unsigned short*)(ws + (48l << 20));

  // 1) convert inputs fp32 -> bf16 (once)
  cvt_x<<<dim3(2048, 3, 1), 256, 0, stream>>>(query, key, value, Xb);

  // 2) transpose+convert weights into proj's tiled LDS image
  cvt_w<<<dim3(16, 16, 3), 256, 0, stream>>>(Wq, Wk, Wv, WTt);

  // 3) fused QKV projections; K/V written as attn's tiled LDS images
  proj_gemm<<<dim3(8, 32, 3), 256, 0, stream>>>(Xb, WTt, bq, bk, bv,
                                                qbuf, ktile, vtile);

  // 4) flash attention (S-transposed, coalesced DMA staging), fp32 output
  attn<<<dim3(32, 32, 1), 256, 0, stream>>>(qbuf, ktile, vtile, table, mask,
                                            (float*)d_out);
}